// Round 5
// baseline (796.572 us; speedup 1.0000x reference)
//
#include <hip/hip_runtime.h>
#include <math.h>

typedef unsigned short u16;
typedef unsigned int   u32;
typedef unsigned long long u64;
typedef float  v16f __attribute__((ext_vector_type(16)));
typedef short  v8s  __attribute__((ext_vector_type(8)));

__device__ __forceinline__ float sigf(float x) { return 1.0f / (1.0f + __expf(-x)); }
__device__ __forceinline__ float tanhfast(float x) { return 2.0f / (1.0f + __expf(-2.0f * x)) - 1.0f; }
__device__ __forceinline__ u16 f2bf(float f) {
    u32 x = __float_as_uint(f);
    u32 r = (x + 0x7fffu + ((x >> 16) & 1u)) >> 16;   // RNE
    return (u16)r;
}

// ---------------------------------------------------------------------
// Conv-as-MFMA constants (verified R4)
// ---------------------------------------------------------------------
#define KE        19
#define SLAB      2048
#define G0_OFF    0
#define G1_OFF    (3 * KE * SLAB)
#define G2_OFF    (7 * KE * SLAB)
#define WKR_TOT   (12 * KE * SLAB)
#define XSTR      312

__global__ __launch_bounds__(256) void k_cprep(const float* __restrict__ w3,
                                               const float* __restrict__ w4,
                                               const float* __restrict__ w5,
                                               u16* __restrict__ wkr) {
    const int gid = blockIdx.x * 256 + threadIdx.x;
    int g, rem;
    if (gid < G1_OFF)      { g = 0; rem = gid; }
    else if (gid < G2_OFF) { g = 1; rem = gid - G1_OFF; }
    else                   { g = 2; rem = gid - G2_OFF; }
    const int fs = 3 + g;
    const int j  = rem & 7;
    const int q  = (rem >> 3) & 1;
    const int f  = (rem >> 4) & 127;
    const int t  = rem >> 11;
    const int ke = t % KE;
    const int kk = t / KE;
    const int e  = ke * 16 + q * 8 + j;
    float v = 0.0f;
    if (f < 100 && e < 300) {
        const float* w = (g == 0) ? w3 : (g == 1) ? w4 : w5;
        v = w[((size_t)f * 300 + e) * fs + kk];
    }
    wkr[gid] = f2bf(v);
}

// =====================================================================
// K1: conv via MFMA (unchanged, R11-proven)
// =====================================================================
__global__ __launch_bounds__(384) void k_conv_mfma(const int* __restrict__ dlg,
                                                   const float* __restrict__ emb,
                                                   const u16* __restrict__ wkr,
                                                   const float* __restrict__ b3,
                                                   const float* __restrict__ b4,
                                                   const float* __restrict__ b5,
                                                   float* __restrict__ feat) {
    __shared__ u16 xT[104 * XSTR];
    __shared__ int toks[96];
    const int u2  = blockIdx.x;
    const int tid = threadIdx.x;
    if (tid < 96) toks[tid] = dlg[u2 * 96 + tid];
    __syncthreads();
    for (int i = tid; i < 96 * 75; i += 384) {
        int t  = i / 75;
        int e4 = i - t * 75;
        int utt = (t >= 48);
        int row = utt * 52 + (t - utt * 48);
        float4 v = *(const float4*)(emb + (size_t)toks[t] * 300 + e4 * 4);
        uint2 o;
        o.x = (u32)f2bf(v.x) | ((u32)f2bf(v.y) << 16);
        o.y = (u32)f2bf(v.z) | ((u32)f2bf(v.w) << 16);
        *(uint2*)&xT[row * XSTR + e4 * 4] = o;
    }
    for (int i = tid; i < 8 * (XSTR / 2); i += 384) {
        int r = i / (XSTR / 2);
        int c = i - r * (XSTR / 2);
        int row = (r < 4) ? (48 + r) : (96 + r - 4);
        *(u32*)&xT[row * XSTR + c * 2] = 0;
    }
    __syncthreads();

    const int wv   = tid >> 6;
    const int lane = tid & 63;
    const int m    = lane & 31;
    const int q    = lane >> 5;

    int abase[3];
#pragma unroll
    for (int mt = 0; mt < 3; ++mt) {
        int r = mt * 32 + m;
        int utt = (r >= 48);
        int p = r - utt * 48;
        abase[mt] = (utt * 52 + p) * XSTR + q * 8;
    }

    int gA, ntA, gB, ntB, kkA, kkB;
    if (wv < 4) { gA = 0; ntA = wv; gB = 2; ntB = wv; kkA = 3; kkB = 5; }
    else        { gA = 1; ntA = (wv - 4) * 2; gB = 1; ntB = ntA + 1; kkA = 4; kkB = 4; }
    const int goffA = (gA == 0) ? G0_OFF : (gA == 1) ? G1_OFF : G2_OFF;
    const int goffB = (gB == 0) ? G0_OFF : (gB == 1) ? G1_OFF : G2_OFF;
    const u16* wA = wkr + goffA + ((ntA * 32 + m) * 2 + q) * 8;
    const u16* wB = wkr + goffB + ((ntB * 32 + m) * 2 + q) * 8;

    v16f accA[3], accB[3];
#pragma unroll
    for (int mt = 0; mt < 3; ++mt) {
#pragma unroll
        for (int r = 0; r < 16; ++r) { accA[mt][r] = 0.0f; accB[mt][r] = 0.0f; }
    }

    const int kmin = (kkA < kkB) ? kkA : kkB;   // waves0-3: 3, waves4-5: 4
    const u16* pA = wA;
    const u16* pB = wB;
    v8s bfA = *(const v8s*)pA;
    v8s bfB = *(const v8s*)pB;
    for (int kk = 0; kk < kmin; ++kk) {
        const int xshift = kk * XSTR;
        for (int ke = 0; ke < KE; ++ke) {
            v8s cA = bfA, cB = bfB;
            pA += SLAB; pB += SLAB;
            bfA = *(const v8s*)pA;             // prefetch (harmless overread at end)
            bfB = *(const v8s*)pB;
            const int xcol = xshift + ke * 16;
#pragma unroll
            for (int mt = 0; mt < 3; ++mt) {
                v8s af = *(const v8s*)&xT[abase[mt] + xcol];
                accA[mt] = __builtin_amdgcn_mfma_f32_32x32x16_bf16(af, cA, accA[mt], 0, 0, 0);
                accB[mt] = __builtin_amdgcn_mfma_f32_32x32x16_bf16(af, cB, accB[mt], 0, 0, 0);
            }
        }
    }
    for (int kk = kmin; kk < kkB; ++kk) {
        const int xshift = kk * XSTR;
        for (int ke = 0; ke < KE; ++ke) {
            v8s cB = bfB;
            pB += SLAB;
            bfB = *(const v8s*)pB;
            const int xcol = xshift + ke * 16;
#pragma unroll
            for (int mt = 0; mt < 3; ++mt) {
                v8s af = *(const v8s*)&xT[abase[mt] + xcol];
                accB[mt] = __builtin_amdgcn_mfma_f32_32x32x16_bf16(af, cB, accB[mt], 0, 0, 0);
            }
        }
    }

    const int PP[3] = {46, 45, 44};
#pragma unroll
    for (int which = 0; which < 2; ++which) {
        const int g  = which ? gB : gA;
        const int nt = which ? ntB : ntA;
        const v16f* acc = which ? accB : accA;
        const float* bg = (g == 0) ? b3 : (g == 1) ? b4 : b5;
        const int f = nt * 32 + m;
        const float bias = (f < 100) ? bg[f] : 0.0f;
        const int Pg = PP[g];
        float v0 = -1e30f, v1 = -1e30f;
#pragma unroll
        for (int mt = 0; mt < 3; ++mt) {
#pragma unroll
            for (int reg = 0; reg < 16; ++reg) {
                int row = (reg & 3) + 8 * (reg >> 2) + 4 * q;
                int r = mt * 32 + row;
                int utt = (r >= 48);
                int p = r - utt * 48;
                if (p < Pg) {
                    float val = acc[mt][reg] + bias;
                    if (utt) v1 = fmaxf(v1, val); else v0 = fmaxf(v0, val);
                }
            }
        }
        v0 = fmaxf(v0, __shfl_xor(v0, 32, 64));
        v1 = fmaxf(v1, __shfl_xor(v1, 32, 64));
        if (q == 0 && f < 100) {
            feat[((size_t)(u2 * 2 + 0)) * 300 + g * 100 + f] = fmaxf(0.0f, v0);
            feat[((size_t)(u2 * 2 + 1)) * 300 + g * 100 + f] = fmaxf(0.0f, v1);
        }
    }
}

// =====================================================================
// K2: xg GEMM; output in MFMA C-fragment order (unchanged)
// =====================================================================
__global__ __launch_bounds__(256) void k_xg(const float* __restrict__ feat,
                                            const float* __restrict__ wih_f, const float* __restrict__ bih_f,
                                            const float* __restrict__ bhh_f,
                                            const float* __restrict__ wih_r, const float* __restrict__ bih_r,
                                            const float* __restrict__ bhh_r,
                                            float* __restrict__ xgF) {
    __shared__ float fls[300 * 36];
    const int bx  = blockIdx.x;
    const int dir = bx >> 8;
    const int t   = (bx >> 2) & 63;
    const int gc  = bx & 3;
    const int tid = threadIdx.x;
    for (int i = tid; i < 32 * 300; i += 256) {
        int b = i / 300;
        int d = i - b * 300;
        fls[d * 36 + b] = feat[((size_t)b * 64 + t) * 300 + d];
    }
    __syncthreads();
    const int g = gc * 256 + tid;
    const float* wih = dir ? wih_r : wih_f;
    const float* bih = dir ? bih_r : bih_f;
    const float* bhh = dir ? bhh_r : bhh_f;
    const float* wr  = wih + (size_t)g * 300;
    const float bias = bih[g] + bhh[g];
    float acc[32];
#pragma unroll
    for (int b = 0; b < 32; ++b) acc[b] = 0.0f;
    for (int d = 0; d < 300; d += 4) {
        float4 wv = *(const float4*)(wr + d);
#pragma unroll
        for (int j = 0; j < 4; ++j) {
            float w = (j == 0) ? wv.x : (j == 1) ? wv.y : (j == 2) ? wv.z : wv.w;
            const float* r = &fls[(d + j) * 36];
#pragma unroll
            for (int bq = 0; bq < 8; ++bq) {
                float4 x = *(const float4*)(r + bq * 4);
                acc[bq * 4 + 0] = fmaf(w, x.x, acc[bq * 4 + 0]);
                acc[bq * 4 + 1] = fmaf(w, x.y, acc[bq * 4 + 1]);
                acc[bq * 4 + 2] = fmaf(w, x.z, acc[bq * 4 + 2]);
                acc[bq * 4 + 3] = fmaf(w, x.w, acc[bq * 4 + 3]);
            }
        }
    }
    const int jj      = tid;
    const int js      = jj >> 6;
    const int n_local = ((jj & 63) << 2) | gc;
    const int nt      = n_local >> 5;
    const int lane_lo = n_local & 31;
    float* base = xgF + (((size_t)(dir * 64 + t) * 32) + js * 8 + nt) * 1024;
#pragma unroll
    for (int b = 0; b < 32; ++b) {
        int q    = (b >> 2) & 1;
        int reg  = (b & 3) + ((b >> 3) << 2);
        base[reg * 64 + lane_lo + (q << 5)] = acc[b] + bias;
    }
}

// =====================================================================
// K_prep3: w_hh -> MFMA B-fragment shards (unchanged)
// =====================================================================
__global__ __launch_bounds__(256) void k_prep3(const float* __restrict__ whh_f,
                                               const float* __restrict__ whh_r,
                                               u16* __restrict__ wpk3) {
    const int gid  = blockIdx.x * 256 + threadIdx.x;    // [0, 524288)
    const int j    = gid & 7;
    const int lane = (gid >> 3) & 63;
    const int kt   = (gid >> 9) & 15;
    const int nt   = (gid >> 13) & 7;
    const int js   = (gid >> 16) & 3;
    const int dir  = (gid >> 18) & 1;
    const int n_local = nt * 32 + (lane & 31);
    const int jjl  = n_local >> 2;
    const int gate = n_local & 3;
    const int k    = kt * 16 + (lane >> 5) * 8 + j;
    const int row  = gate * 256 + js * 64 + jjl;
    const float* whh = dir ? whh_r : whh_f;
    wpk3[gid] = f2bf(whh[(size_t)row * 256 + k]);
}

// =====================================================================
// K3 v10: LSTM, BATCH-SPLIT — zero inter-block communication.
// 8 blocks = 2 dir x 4 batch-groups (8 batch rows each). Each block
// computes ALL 1024 gates for its 8 batches: the recurrence h[b,s] ->
// h[b,s+1] is block-local (h lives in LDS), so the R9-R13 record/spin
// exchange machinery disappears entirely. Costs accepted: MFMA M=8/32
// rows used (4x MFMA work, trivial at 0.3% util) and W_hh B-fragments
// re-streamed from L2 each step (1 MB/block-step, XCD-L2-resident).
// A-fragments (h) are loaded once per step and reused across all 4
// N-chunks. Gate transpose via per-wave-private LDS slices (no barrier).
// Per-gate arithmetic (MFMA k-order + EW) identical to R13 -> same
// numerics. Reuses wpk3/xgF layouts verbatim.
// =====================================================================
__global__ __launch_bounds__(512) void k_lstm3(const u16* __restrict__ wpk3,
                                               const float* __restrict__ xgF,
                                               float* __restrict__ hseq) {
    __shared__ u32   hbuf[32 * 132];          // h as bf16, row=local batch, 264 u16 cols
    __shared__ float slab[8 * 320];           // per-wave 8x40 f32 transpose slices
    const int dir = blockIdx.x >> 2;
    const int bg  = blockIdx.x & 3;           // batch group: global b = bg*8 + [0,8)
    const int tid = threadIdx.x;
    const int w   = tid >> 6;                 // wave 0..7 = N-tile nt
    const int l   = tid & 63;
    const int m   = l & 31;
    const int q   = l >> 5;

    // zero h state (rows 8..31 stay zero forever -> A-frag padding rows)
    for (int i = tid; i < 32 * 132; i += 512) hbuf[i] = 0u;

    float* sl = &slab[w * 320];
    const int bl = l >> 3;                    // local batch for EW / h-write
    const int jj = l & 7;                     // hidden sub-index within tile
    u16* hb16 = (u16*)hbuf;

    float cst[4], hval[4];
#pragma unroll
    for (int c2 = 0; c2 < 4; ++c2) { cst[c2] = 0.0f; hval[c2] = 0.0f; }

    float* hout = hseq + (size_t)dir * 64 * 32 * 256;

    for (int s = 0; s < 64; ++s) {
        const int t = dir ? (63 - s) : s;
        __syncthreads();                      // h state (hbuf) ready

        // A-fragments: h[local b rows][K=256] — shared by all 4 N-chunks
        v8s af[16];
#pragma unroll
        for (int kt = 0; kt < 16; ++kt)
            af[kt] = *(const v8s*)&hbuf[m * 132 + kt * 8 + q * 4];

#pragma unroll
        for (int c2 = 0; c2 < 4; ++c2) {      // N-chunk = js of the old layout
            const u16* wb = wpk3 + ((((size_t)dir * 4 + c2) * 8 + w) * 16) * 512 + (size_t)l * 8;
            v8s Bfc[16];
#pragma unroll
            for (int kt = 0; kt < 16; ++kt) Bfc[kt] = *(const v8s*)(wb + kt * 512);

            // xg init: only the 4 acc rows that map to our 8 real batches
            const float* xb = xgF + (((size_t)(dir * 64 + t) * 32) + c2 * 8 + w) * 1024
                            + bg * 256 + q * 32 + m;
            v16f acc;
#pragma unroll
            for (int r = 0; r < 4; ++r) acc[r] = xb[r * 64];
#pragma unroll
            for (int r = 4; r < 16; ++r) acc[r] = 0.0f;

#pragma unroll
            for (int kt = 0; kt < 16; ++kt)
                acc = __builtin_amdgcn_mfma_f32_32x32x16_bf16(af[kt], Bfc[kt], acc, 0, 0, 0);

            // per-wave transpose: C[b_loc=(r&3)+4q][n=m] -> (b, gate-quad)
#pragma unroll
            for (int r = 0; r < 4; ++r) sl[(r + 4 * q) * 40 + m] = acc[r];
            asm volatile("s_waitcnt lgkmcnt(0)" ::: "memory");   // wave-local W->R
            float4 gv = *(const float4*)&sl[bl * 40 + jj * 4];   // i,f,g,o of one j
            float i_ = sigf(gv.x), f_ = sigf(gv.y);
            float g_ = tanhfast(gv.z), o_ = sigf(gv.w);
            cst[c2]  = f_ * cst[c2] + i_ * g_;
            hval[c2] = o_ * tanhfast(cst[c2]);
        }

        __syncthreads();                      // all hbuf A-reads of step s done
#pragma unroll
        for (int c2 = 0; c2 < 4; ++c2) {
            const int j = c2 * 64 + 8 * w + jj;
            hb16[bl * 264 + j] = f2bf(hval[c2]);
            hout[((size_t)t * 32 + bg * 8 + bl) * 256 + j] = hval[c2];
        }
    }
}

// =====================================================================
// K4: head (unchanged)
// =====================================================================
__global__ __launch_bounds__(256) void k_head(const float* __restrict__ hseq,
                                              const float* __restrict__ hw,
                                              const float* __restrict__ hb,
                                              float* __restrict__ out) {
    const int id = blockIdx.x * 256 + threadIdx.x;
    const int o  = id & 31;
    const int u  = id >> 5;
    const int b  = u >> 6, t = u & 63;
    const float* pf = hseq + ((size_t)t * 32 + b) * 256;
    const float* pr = hseq + (size_t)64 * 32 * 256 + ((size_t)t * 32 + b) * 256;
    const float* wo = hw + (size_t)o * 512;
    float acc = hb[o];
    for (int j = 0; j < 256; j += 4) {
        float4 wa = *(const float4*)(wo + j);
        float4 wb = *(const float4*)(wo + 256 + j);
        float4 fa = *(const float4*)(pf + j);
        float4 fb = *(const float4*)(pr + j);
        acc = fmaf(wa.x, fa.x, acc); acc = fmaf(wa.y, fa.y, acc);
        acc = fmaf(wa.z, fa.z, acc); acc = fmaf(wa.w, fa.w, acc);
        acc = fmaf(wb.x, fb.x, acc); acc = fmaf(wb.y, fb.y, acc);
        acc = fmaf(wb.z, fb.z, acc); acc = fmaf(wb.w, fb.w, acc);
    }
    out[id] = sigf(acc);
}

// =====================================================================
extern "C" void kernel_launch(void* const* d_in, const int* in_sizes, int n_in,
                              void* d_out, int out_size, void* d_ws, size_t ws_size,
                              hipStream_t stream) {
    const int*   dlg   = (const int*)d_in[0];
    const float* emb   = (const float*)d_in[1];
    const float* w3    = (const float*)d_in[2];  const float* b3    = (const float*)d_in[3];
    const float* w4    = (const float*)d_in[4];  const float* b4    = (const float*)d_in[5];
    const float* w5    = (const float*)d_in[6];  const float* b5    = (const float*)d_in[7];
    const float* wih_f = (const float*)d_in[8];  const float* whh_f = (const float*)d_in[9];
    const float* bih_f = (const float*)d_in[10]; const float* bhh_f = (const float*)d_in[11];
    const float* wih_r = (const float*)d_in[12]; const float* whh_r = (const float*)d_in[13];
    const float* bih_r = (const float*)d_in[14]; const float* bhh_r = (const float*)d_in[15];
    const float* hw    = (const float*)d_in[16]; const float* hb    = (const float*)d_in[17];
    float* out = (float*)d_out;

    float* f     = (float*)d_ws;
    float* feat  = f;                         // 614400
    float* xgF   = f + 614400;                // 4194304
    float* hseq  = f + 4808704;               // 1048576
    u16*   wkr   = (u16*)(f + 5857280);       // 466944 u16
    u16*   wpk3  = (u16*)(f + 6090752);       // 524288 u16
    // total ~25.4 MB

    hipLaunchKernelGGL(k_cprep, dim3(WKR_TOT / 256), dim3(256), 0, stream,
                       w3, w4, w5, wkr);
    hipLaunchKernelGGL(k_prep3, dim3(2048), dim3(256), 0, stream,
                       whh_f, whh_r, wpk3);
    hipLaunchKernelGGL(k_conv_mfma, dim3(1024), dim3(384), 0, stream,
                       dlg, emb, wkr, b3, b4, b5, feat);
    hipLaunchKernelGGL(k_xg, dim3(512), dim3(256), 0, stream,
                       feat, wih_f, bih_f, bhh_f, wih_r, bih_r, bhh_r, xgF);
    hipLaunchKernelGGL(k_lstm3, dim3(8), dim3(512), 0, stream,
                       wpk3, xgF, hseq);
    hipLaunchKernelGGL(k_head, dim3(256), dim3(256), 0, stream,
                       hseq, hw, hb, out);
}

// Round 7
// 550.202 us; speedup vs baseline: 1.4478x; 1.4478x over previous
//
#include <hip/hip_runtime.h>
#include <math.h>

typedef unsigned short u16;
typedef unsigned int   u32;
typedef unsigned long long u64;
typedef float  v16f __attribute__((ext_vector_type(16)));
typedef short  v8s  __attribute__((ext_vector_type(8)));
typedef unsigned int v4u __attribute__((ext_vector_type(4)));

__device__ __forceinline__ float sigf(float x) { return 1.0f / (1.0f + __expf(-x)); }
__device__ __forceinline__ float tanhfast(float x) { return 2.0f / (1.0f + __expf(-2.0f * x)) - 1.0f; }
__device__ __forceinline__ u16 f2bf(float f) {
    u32 x = __float_as_uint(f);
    u32 r = (x + 0x7fffu + ((x >> 16) & 1u)) >> 16;   // RNE
    return (u16)r;
}

// Agent-scope (sc1) 16B record ops (R13-proven): coherence point = IC.
#define LD3SYS(v0, v1, v2, p0, p1, p2)                                        \
    asm volatile("global_load_dwordx4 %0, %3, off sc1\n\t"                    \
                 "global_load_dwordx4 %1, %4, off sc1\n\t"                    \
                 "global_load_dwordx4 %2, %5, off sc1\n\t"                    \
                 "s_waitcnt vmcnt(0)"                                         \
                 : "=&v"(v0), "=&v"(v1), "=&v"(v2)                            \
                 : "v"(p0), "v"(p1), "v"(p2)                                  \
                 : "memory")

#define ST16SYS(p, v)                                                         \
    asm volatile("global_store_dwordx4 %0, %1, off sc1"                       \
                 :: "v"(p), "v"(v) : "memory")

// ---------------------------------------------------------------------
// Conv-as-MFMA constants (verified R4)
// ---------------------------------------------------------------------
#define KE        19
#define SLAB      2048
#define G0_OFF    0
#define G1_OFF    (3 * KE * SLAB)
#define G2_OFF    (7 * KE * SLAB)
#define WKR_TOT   (12 * KE * SLAB)
#define XSTR      312

__global__ __launch_bounds__(256) void k_cprep(const float* __restrict__ w3,
                                               const float* __restrict__ w4,
                                               const float* __restrict__ w5,
                                               u16* __restrict__ wkr) {
    const int gid = blockIdx.x * 256 + threadIdx.x;
    int g, rem;
    if (gid < G1_OFF)      { g = 0; rem = gid; }
    else if (gid < G2_OFF) { g = 1; rem = gid - G1_OFF; }
    else                   { g = 2; rem = gid - G2_OFF; }
    const int fs = 3 + g;
    const int j  = rem & 7;
    const int q  = (rem >> 3) & 1;
    const int f  = (rem >> 4) & 127;
    const int t  = rem >> 11;
    const int ke = t % KE;
    const int kk = t / KE;
    const int e  = ke * 16 + q * 8 + j;
    float v = 0.0f;
    if (f < 100 && e < 300) {
        const float* w = (g == 0) ? w3 : (g == 1) ? w4 : w5;
        v = w[((size_t)f * 300 + e) * fs + kk];
    }
    wkr[gid] = f2bf(v);
}

// =====================================================================
// K1: conv via MFMA (unchanged, R11-proven)
// =====================================================================
__global__ __launch_bounds__(384) void k_conv_mfma(const int* __restrict__ dlg,
                                                   const float* __restrict__ emb,
                                                   const u16* __restrict__ wkr,
                                                   const float* __restrict__ b3,
                                                   const float* __restrict__ b4,
                                                   const float* __restrict__ b5,
                                                   float* __restrict__ feat) {
    __shared__ u16 xT[104 * XSTR];
    __shared__ int toks[96];
    const int u2  = blockIdx.x;
    const int tid = threadIdx.x;
    if (tid < 96) toks[tid] = dlg[u2 * 96 + tid];
    __syncthreads();
    for (int i = tid; i < 96 * 75; i += 384) {
        int t  = i / 75;
        int e4 = i - t * 75;
        int utt = (t >= 48);
        int row = utt * 52 + (t - utt * 48);
        float4 v = *(const float4*)(emb + (size_t)toks[t] * 300 + e4 * 4);
        uint2 o;
        o.x = (u32)f2bf(v.x) | ((u32)f2bf(v.y) << 16);
        o.y = (u32)f2bf(v.z) | ((u32)f2bf(v.w) << 16);
        *(uint2*)&xT[row * XSTR + e4 * 4] = o;
    }
    for (int i = tid; i < 8 * (XSTR / 2); i += 384) {
        int r = i / (XSTR / 2);
        int c = i - r * (XSTR / 2);
        int row = (r < 4) ? (48 + r) : (96 + r - 4);
        *(u32*)&xT[row * XSTR + c * 2] = 0;
    }
    __syncthreads();

    const int wv   = tid >> 6;
    const int lane = tid & 63;
    const int m    = lane & 31;
    const int q    = lane >> 5;

    int abase[3];
#pragma unroll
    for (int mt = 0; mt < 3; ++mt) {
        int r = mt * 32 + m;
        int utt = (r >= 48);
        int p = r - utt * 48;
        abase[mt] = (utt * 52 + p) * XSTR + q * 8;
    }

    int gA, ntA, gB, ntB, kkA, kkB;
    if (wv < 4) { gA = 0; ntA = wv; gB = 2; ntB = wv; kkA = 3; kkB = 5; }
    else        { gA = 1; ntA = (wv - 4) * 2; gB = 1; ntB = ntA + 1; kkA = 4; kkB = 4; }
    const int goffA = (gA == 0) ? G0_OFF : (gA == 1) ? G1_OFF : G2_OFF;
    const int goffB = (gB == 0) ? G0_OFF : (gB == 1) ? G1_OFF : G2_OFF;
    const u16* wA = wkr + goffA + ((ntA * 32 + m) * 2 + q) * 8;
    const u16* wB = wkr + goffB + ((ntB * 32 + m) * 2 + q) * 8;

    v16f accA[3], accB[3];
#pragma unroll
    for (int mt = 0; mt < 3; ++mt) {
#pragma unroll
        for (int r = 0; r < 16; ++r) { accA[mt][r] = 0.0f; accB[mt][r] = 0.0f; }
    }

    const int kmin = (kkA < kkB) ? kkA : kkB;   // waves0-3: 3, waves4-5: 4
    const u16* pA = wA;
    const u16* pB = wB;
    v8s bfA = *(const v8s*)pA;
    v8s bfB = *(const v8s*)pB;
    for (int kk = 0; kk < kmin; ++kk) {
        const int xshift = kk * XSTR;
        for (int ke = 0; ke < KE; ++ke) {
            v8s cA = bfA, cB = bfB;
            pA += SLAB; pB += SLAB;
            bfA = *(const v8s*)pA;             // prefetch (harmless overread at end)
            bfB = *(const v8s*)pB;
            const int xcol = xshift + ke * 16;
#pragma unroll
            for (int mt = 0; mt < 3; ++mt) {
                v8s af = *(const v8s*)&xT[abase[mt] + xcol];
                accA[mt] = __builtin_amdgcn_mfma_f32_32x32x16_bf16(af, cA, accA[mt], 0, 0, 0);
                accB[mt] = __builtin_amdgcn_mfma_f32_32x32x16_bf16(af, cB, accB[mt], 0, 0, 0);
            }
        }
    }
    for (int kk = kmin; kk < kkB; ++kk) {
        const int xshift = kk * XSTR;
        for (int ke = 0; ke < KE; ++ke) {
            v8s cB = bfB;
            pB += SLAB;
            bfB = *(const v8s*)pB;
            const int xcol = xshift + ke * 16;
#pragma unroll
            for (int mt = 0; mt < 3; ++mt) {
                v8s af = *(const v8s*)&xT[abase[mt] + xcol];
                accB[mt] = __builtin_amdgcn_mfma_f32_32x32x16_bf16(af, cB, accB[mt], 0, 0, 0);
            }
        }
    }

    const int PP[3] = {46, 45, 44};
#pragma unroll
    for (int which = 0; which < 2; ++which) {
        const int g  = which ? gB : gA;
        const int nt = which ? ntB : ntA;
        const v16f* acc = which ? accB : accA;
        const float* bg = (g == 0) ? b3 : (g == 1) ? b4 : b5;
        const int f = nt * 32 + m;
        const float bias = (f < 100) ? bg[f] : 0.0f;
        const int Pg = PP[g];
        float v0 = -1e30f, v1 = -1e30f;
#pragma unroll
        for (int mt = 0; mt < 3; ++mt) {
#pragma unroll
            for (int reg = 0; reg < 16; ++reg) {
                int row = (reg & 3) + 8 * (reg >> 2) + 4 * q;
                int r = mt * 32 + row;
                int utt = (r >= 48);
                int p = r - utt * 48;
                if (p < Pg) {
                    float val = acc[mt][reg] + bias;
                    if (utt) v1 = fmaxf(v1, val); else v0 = fmaxf(v0, val);
                }
            }
        }
        v0 = fmaxf(v0, __shfl_xor(v0, 32, 64));
        v1 = fmaxf(v1, __shfl_xor(v1, 32, 64));
        if (q == 0 && f < 100) {
            feat[((size_t)(u2 * 2 + 0)) * 300 + g * 100 + f] = fmaxf(0.0f, v0);
            feat[((size_t)(u2 * 2 + 1)) * 300 + g * 100 + f] = fmaxf(0.0f, v1);
        }
    }
}

// =====================================================================
// K2: xg GEMM; output in MFMA C-fragment order (unchanged)
// =====================================================================
__global__ __launch_bounds__(256) void k_xg(const float* __restrict__ feat,
                                            const float* __restrict__ wih_f, const float* __restrict__ bih_f,
                                            const float* __restrict__ bhh_f,
                                            const float* __restrict__ wih_r, const float* __restrict__ bih_r,
                                            const float* __restrict__ bhh_r,
                                            float* __restrict__ xgF) {
    __shared__ float fls[300 * 36];
    const int bx  = blockIdx.x;
    const int dir = bx >> 8;
    const int t   = (bx >> 2) & 63;
    const int gc  = bx & 3;
    const int tid = threadIdx.x;
    for (int i = tid; i < 32 * 300; i += 256) {
        int b = i / 300;
        int d = i - b * 300;
        fls[d * 36 + b] = feat[((size_t)b * 64 + t) * 300 + d];
    }
    __syncthreads();
    const int g = gc * 256 + tid;
    const float* wih = dir ? wih_r : wih_f;
    const float* bih = dir ? bih_r : bih_f;
    const float* bhh = dir ? bhh_r : bhh_f;
    const float* wr  = wih + (size_t)g * 300;
    const float bias = bih[g] + bhh[g];
    float acc[32];
#pragma unroll
    for (int b = 0; b < 32; ++b) acc[b] = 0.0f;
    for (int d = 0; d < 300; d += 4) {
        float4 wv = *(const float4*)(wr + d);
#pragma unroll
        for (int j = 0; j < 4; ++j) {
            float w = (j == 0) ? wv.x : (j == 1) ? wv.y : (j == 2) ? wv.z : wv.w;
            const float* r = &fls[(d + j) * 36];
#pragma unroll
            for (int bq = 0; bq < 8; ++bq) {
                float4 x = *(const float4*)(r + bq * 4);
                acc[bq * 4 + 0] = fmaf(w, x.x, acc[bq * 4 + 0]);
                acc[bq * 4 + 1] = fmaf(w, x.y, acc[bq * 4 + 1]);
                acc[bq * 4 + 2] = fmaf(w, x.z, acc[bq * 4 + 2]);
                acc[bq * 4 + 3] = fmaf(w, x.w, acc[bq * 4 + 3]);
            }
        }
    }
    const int jj      = tid;
    const int js      = jj >> 6;
    const int n_local = ((jj & 63) << 2) | gc;
    const int nt      = n_local >> 5;
    const int lane_lo = n_local & 31;
    float* base = xgF + (((size_t)(dir * 64 + t) * 32) + js * 8 + nt) * 1024;
#pragma unroll
    for (int b = 0; b < 32; ++b) {
        int q    = (b >> 2) & 1;
        int reg  = (b & 3) + ((b >> 3) << 2);
        base[reg * 64 + lane_lo + (q << 5)] = acc[b] + bias;
    }
}

// =====================================================================
// K_prep3: w_hh -> MFMA B-fragment shards (unchanged)
// =====================================================================
__global__ __launch_bounds__(256) void k_prep3(const float* __restrict__ whh_f,
                                               const float* __restrict__ whh_r,
                                               u16* __restrict__ wpk3) {
    const int gid  = blockIdx.x * 256 + threadIdx.x;    // [0, 524288)
    const int j    = gid & 7;
    const int lane = (gid >> 3) & 63;
    const int kt   = (gid >> 9) & 15;
    const int nt   = (gid >> 13) & 7;
    const int js   = (gid >> 16) & 3;
    const int dir  = (gid >> 18) & 1;
    const int n_local = nt * 32 + (lane & 31);
    const int jjl  = n_local >> 2;
    const int gate = n_local & 3;
    const int k    = kt * 16 + (lane >> 5) * 8 + j;
    const int row  = gate * 256 + js * 64 + jjl;
    const float* whh = dir ? whh_r : whh_f;
    wpk3[gid] = f2bf(whh[(size_t)row * 256 + k]);
}

// k_init: zero all 8192 h-exchange records (2 dir x 2 parity x 2048)
__global__ __launch_bounds__(256) void k_init(v4u* __restrict__ hxrec) {
    const int id = blockIdx.x * 256 + threadIdx.x;
    v4u z; z[0] = 0u; z[1] = 0u; z[2] = 0u; z[3] = 0u;
    hxrec[id] = z;
}

// =====================================================================
// K3 v13: gate-split (R13-proven protocol) + serial-chain cuts that are
// arithmetic-neutral (R17 post-mortem: the 2x8 MFMA chain split shifted
// absmax 0.0117 -> 0.0156, over threshold; reverted):
//  (a) cross-step xgF register prefetch (acc init never waits on global)
//  (b) wave-local EW: wave w's 32 MFMA cols = complete i,f,g,o quads for
//      j in [8w,8w+8) -> per-wave 32x36 slab transpose (lgkmcnt-ordered),
//      replacing block-wide gbuf + its barrier
// MFMA chain: single dependent 16-chain in R13's exact kt order
// (bit-identical gate preacts). Exchange records byte-identical to R13.
// =====================================================================
__global__ __launch_bounds__(512) void k_lstm3(const u16* __restrict__ wpk3,
                                               const float* __restrict__ xgF,
                                               u32* __restrict__ hxrec,
                                               float* __restrict__ hseq) {
    __shared__ u32   hbuf[32 * 132];          // h as bf16-pairs, row stride 132 dw
    __shared__ float slab[8 * 32 * 36];       // per-wave 32x36 f32 transpose slices
    const int dir = blockIdx.x >> 2;
    const int js  = blockIdx.x & 3;
    const int tid = threadIdx.x;
    const int w   = tid >> 6;                 // n-tile 0..7
    const int l   = tid & 63;
    const int m   = l & 31;
    const int q   = l >> 5;

    v8s Bf[16];
    {
        const u16* wb = wpk3 + ((((size_t)dir * 4 + js) * 8 + w) * 16) * 512 + (size_t)l * 8;
#pragma unroll
        for (int kt = 0; kt < 16; ++kt) Bf[kt] = *(const v8s*)(wb + kt * 512);
    }

    // EW ownership (wave-local): lane l -> batch bl, j-pair jp; handles
    // hidden j_global = js*64 + 8w + 4*jp + c, c=0..3
    const int jp = l & 1;
    const int bl = l >> 1;
    float cst[4], hval[4];
#pragma unroll
    for (int c = 0; c < 4; ++c) { cst[c] = 0.0f; hval[c] = 0.0f; }

    float* hout = hseq + (size_t)dir * 64 * 32 * 256;
    u32* hx_d   = hxrec + (size_t)dir * 2 * 2048 * 4;   // u32 units
    const u32* hx0 = hx_d;                    // parity-0 slot
    const u32* hx1 = hx_d + 2048 * 4;         // parity-1 slot

    // consumer record offsets (R13-identical): 48 peer q64-slots x 32 b
    int roff[3], hoff[3];
#pragma unroll
    for (int i = 0; i < 3; ++i) {
        int flat = i * 512 + tid;
        int b    = flat / 48;
        int r    = flat - b * 48;
        int q64  = r + (r >= js * 16 ? 16 : 0);
        roff[i]  = (b * 64 + q64) * 4;
        hoff[i]  = b * 132 + q64 * 2;
    }
    // producer slot: (batch bl, q64 = js*16 + 2w + jp)
    const int woff = (bl * 64 + js * 16 + 2 * w + jp) * 4;
    const int hown = bl * 132 + (js * 16 + 2 * w + jp) * 2;

    float* sl = &slab[w * 32 * 36];

    // prefetch xg for s=0
    float xcur[16];
    {
        const int t0 = dir ? 63 : 0;
        const float* xb = xgF + (((size_t)(dir * 64 + t0) * 32) + js * 8 + w) * 1024 + l;
#pragma unroll
        for (int r = 0; r < 16; ++r) xcur[r] = xb[r * 64];
    }

    for (int s = 0; s < 64; ++s) {
        v16f acc;
#pragma unroll
        for (int r = 0; r < 16; ++r) acc[r] = xcur[r];
        if (s < 63) {                          // prefetch next step's xg
            const int tn = dir ? (62 - s) : (s + 1);
            const float* xb = xgF + (((size_t)(dir * 64 + tn) * 32) + js * 8 + w) * 1024 + l;
#pragma unroll
            for (int r = 0; r < 16; ++r) xcur[r] = xb[r * 64];
        }

        if (s > 0) {
            // own pack (hval of step s-1)
            u64 pk = (u64)f2bf(hval[0]) | ((u64)f2bf(hval[1]) << 16)
                   | ((u64)f2bf(hval[2]) << 32) | ((u64)f2bf(hval[3]) << 48);
            *(u64*)&hbuf[hown] = pk;
            // spin for 3 peer records (tag == s)
            const u32* hxs = (s & 1) ? hx1 : hx0;
            const u32* p0 = hxs + roff[0];
            const u32* p1 = hxs + roff[1];
            const u32* p2 = hxs + roff[2];
            v4u v0, v1, v2;
            LD3SYS(v0, v1, v2, p0, p1, p2);
            const u32 ts = (u32)s;
            u32 guard = 0;
            while (v0[2] != ts || v1[2] != ts || v2[2] != ts) {
                if (++guard > (1u << 22)) break;
                LD3SYS(v0, v1, v2, p0, p1, p2);
            }
            *(u64*)&hbuf[hoff[0]] = (u64)v0[0] | ((u64)v0[1] << 32);
            *(u64*)&hbuf[hoff[1]] = (u64)v1[0] | ((u64)v1[1] << 32);
            *(u64*)&hbuf[hoff[2]] = (u64)v2[0] | ((u64)v2[1] << 32);
        } else {
            for (int i = tid; i < 32 * 132; i += 512) hbuf[i] = 0u;
        }
        __syncthreads();                      // A: hbuf(s) ready

        v8s af[16];
#pragma unroll
        for (int kt = 0; kt < 16; ++kt)
            af[kt] = *(const v8s*)&hbuf[m * 132 + kt * 8 + q * 4];
        __syncthreads();                      // B: hbuf free for s+1

        // single dependent chain, R13's exact kt order -> bit-identical
#pragma unroll
        for (int kt = 0; kt < 16; ++kt)
            acc = __builtin_amdgcn_mfma_f32_32x32x16_bf16(af[kt], Bf[kt], acc, 0, 0, 0);

        // per-wave transpose: C[row=batch][col=m] -> (bl, gate quads)
#pragma unroll
        for (int r = 0; r < 16; ++r) {
            int row = (r & 3) + 8 * (r >> 2) + 4 * q;
            sl[row * 36 + m] = acc[r];
        }
        // wave-local W->R ordering: compiler inserts lgkmcnt (same buffer)
#pragma unroll
        for (int c = 0; c < 4; ++c) {
            float4 gv = *(const float4*)&sl[bl * 36 + jp * 16 + c * 4];
            float i_ = sigf(gv.x), f_ = sigf(gv.y);
            float g_ = tanhfast(gv.z), o_ = sigf(gv.w);
            cst[c]  = f_ * cst[c] + i_ * g_;
            hval[c] = o_ * tanhfast(cst[c]);
        }

        {
            const int t = dir ? (63 - s) : s;
            u64 pk = (u64)f2bf(hval[0]) | ((u64)f2bf(hval[1]) << 16)
                   | ((u64)f2bf(hval[2]) << 32) | ((u64)f2bf(hval[3]) << 48);
            v4u rec;
            rec[0] = (u32)pk;
            rec[1] = (u32)(pk >> 32);
            rec[2] = (u32)(s + 1);            // tag = step the record feeds
            rec[3] = 0u;
            u32* pw = (u32*)(((s & 1) ? hx0 : hx1) + woff);   // parity (s+1)&1
            ST16SYS(pw, rec);
            float4 hv4 = make_float4(hval[0], hval[1], hval[2], hval[3]);
            *(float4*)&hout[((size_t)t * 32 + bl) * 256 + js * 64 + 8 * w + 4 * jp] = hv4;
        }
    }
}

// =====================================================================
// K4: head (unchanged)
// =====================================================================
__global__ __launch_bounds__(256) void k_head(const float* __restrict__ hseq,
                                              const float* __restrict__ hw,
                                              const float* __restrict__ hb,
                                              float* __restrict__ out) {
    const int id = blockIdx.x * 256 + threadIdx.x;
    const int o  = id & 31;
    const int u  = id >> 5;
    const int b  = u >> 6, t = u & 63;
    const float* pf = hseq + ((size_t)t * 32 + b) * 256;
    const float* pr = hseq + (size_t)64 * 32 * 256 + ((size_t)t * 32 + b) * 256;
    const float* wo = hw + (size_t)o * 512;
    float acc = hb[o];
    for (int j = 0; j < 256; j += 4) {
        float4 wa = *(const float4*)(wo + j);
        float4 wb = *(const float4*)(wo + 256 + j);
        float4 fa = *(const float4*)(pf + j);
        float4 fb = *(const float4*)(pr + j);
        acc = fmaf(wa.x, fa.x, acc); acc = fmaf(wa.y, fa.y, acc);
        acc = fmaf(wa.z, fa.z, acc); acc = fmaf(wa.w, fa.w, acc);
        acc = fmaf(wb.x, fb.x, acc); acc = fmaf(wb.y, fb.y, acc);
        acc = fmaf(wb.z, fb.z, acc); acc = fmaf(wb.w, fb.w, acc);
    }
    out[id] = sigf(acc);
}

// =====================================================================
extern "C" void kernel_launch(void* const* d_in, const int* in_sizes, int n_in,
                              void* d_out, int out_size, void* d_ws, size_t ws_size,
                              hipStream_t stream) {
    const int*   dlg   = (const int*)d_in[0];
    const float* emb   = (const float*)d_in[1];
    const float* w3    = (const float*)d_in[2];  const float* b3    = (const float*)d_in[3];
    const float* w4    = (const float*)d_in[4];  const float* b4    = (const float*)d_in[5];
    const float* w5    = (const float*)d_in[6];  const float* b5    = (const float*)d_in[7];
    const float* wih_f = (const float*)d_in[8];  const float* whh_f = (const float*)d_in[9];
    const float* bih_f = (const float*)d_in[10]; const float* bhh_f = (const float*)d_in[11];
    const float* wih_r = (const float*)d_in[12]; const float* whh_r = (const float*)d_in[13];
    const float* bih_r = (const float*)d_in[14]; const float* bhh_r = (const float*)d_in[15];
    const float* hw    = (const float*)d_in[16]; const float* hb    = (const float*)d_in[17];
    float* out = (float*)d_out;

    float* f     = (float*)d_ws;
    float* feat  = f;                         // 614400
    float* xgF   = f + 614400;                // 4194304
    float* hseq  = f + 4808704;               // 1048576
    u16*   wkr   = (u16*)(f + 5857280);       // 466944 u16
    u16*   wpk3  = (u16*)(f + 6090752);       // 524288 u16
    u32*   hxrec = (u32*)(f + 6352896);       // 8192 records x 16B
    // total ~25.5 MB

    hipLaunchKernelGGL(k_init, dim3(32), dim3(256), 0, stream, (v4u*)hxrec);
    hipLaunchKernelGGL(k_cprep, dim3(WKR_TOT / 256), dim3(256), 0, stream,
                       w3, w4, w5, wkr);
    hipLaunchKernelGGL(k_prep3, dim3(2048), dim3(256), 0, stream,
                       whh_f, whh_r, wpk3);
    hipLaunchKernelGGL(k_conv_mfma, dim3(1024), dim3(384), 0, stream,
                       dlg, emb, wkr, b3, b4, b5, feat);
    hipLaunchKernelGGL(k_xg, dim3(512), dim3(256), 0, stream,
                       feat, wih_f, bih_f, bhh_f, wih_r, bih_r, bhh_r, xgF);
    hipLaunchKernelGGL(k_lstm3, dim3(8), dim3(512), 0, stream,
                       wpk3, xgF, hxrec, hseq);
    hipLaunchKernelGGL(k_head, dim3(256), dim3(256), 0, stream,
                       hseq, hw, hb, out);
}